// Round 3
// baseline (108.538 us; speedup 1.0000x reference)
//
#include <hip/hip_runtime.h>
#include <hip/hip_bf16.h>

namespace {

constexpr int MM = 64;
constexpr int KK = 4096;
constexpr int NN = 11008;
constexpr int NZROW = NN / 8;       // 1376
constexpr int BN = 128;             // cols per block = 4 waves x 32
constexpr int KSPLIT = 8;
constexpr int KSEG = KK / KSPLIT;   // 512
constexpr int NTILES = NN / BN;     // 86
constexpr int BK = 32;              // k per chunk (one MFMA K)
constexpr int NCH = KSEG / BK;      // 16 chunks
constexpr int NG = 4;               // scale-groups per kseg (GROUP=128)
// ws layout: [0, 22.5MB) fp32 partials; [22.5MB, +512KB) bf16 x
constexpr size_t XB_OFF_BYTES = (size_t)KSPLIT * MM * NN * 4;   // 22,544,384 (16B aligned)
constexpr size_t WS_NEED = XB_OFF_BYTES + (size_t)MM * KK * 2;  // +512 KB

typedef float f32x4 __attribute__((ext_vector_type(4)));
typedef short s16x8 __attribute__((ext_vector_type(8)));
typedef int   i32x4 __attribute__((ext_vector_type(4)));

__device__ __forceinline__ int pack_bf16(float a, float b) {
  union { __hip_bfloat162 h; int i; } u;
  u.h.x = __float2bfloat16(a);
  u.h.y = __float2bfloat16(b);
  return u.i;
}

// x fp32 -> bf16, once per launch. 512 KB out, ~1 us.
__global__ __launch_bounds__(256) void xcvt_kernel(
    const float* __restrict__ x, unsigned short* __restrict__ xb)
{
  const int i8 = (blockIdx.x * 256 + threadIdx.x) * 8;
  const f32x4 a = *(const f32x4*)(x + i8);
  const f32x4 b = *(const f32x4*)(x + i8 + 4);
  i32x4 p;
  p.x = pack_bf16(a.x, a.y);
  p.y = pack_bf16(a.z, a.w);
  p.z = pack_bf16(b.x, b.y);
  p.w = pack_bf16(b.z, b.w);
  *(i32x4*)(xb + i8) = p;
}

// fallback path only: out[m][n] = bias[n], atomics on top
__global__ __launch_bounds__(256) void prep_kernel(
    const float* __restrict__ bias, float* __restrict__ out)
{
  const int i = blockIdx.x * 256 + threadIdx.x;
  out[i] = bias[i % NN];
}

// ws path: out = bias + sum of KSPLIT partials
__global__ __launch_bounds__(256) void reduce_kernel(
    const float* __restrict__ ws, const float* __restrict__ bias,
    float* __restrict__ out)
{
  const int i4 = (blockIdx.x * 256 + threadIdx.x) * 4;
  f32x4 acc = *(const f32x4*)(bias + (i4 % NN));
  #pragma unroll
  for (int s = 0; s < KSPLIT; ++s)
    acc += *(const f32x4*)(ws + (size_t)s * (MM * NN) + i4);
  *(f32x4*)(out + i4) = acc;
}

// R8: zero-LDS, zero-barrier gemm. A-fragments come straight from the
// pre-converted bf16 x (L2-resident: 128 KB per kseg, reused by 86 column
// tiles), depth-1 prefetched into a pA[2][4] ring. B is dequantized
// qw->VGPR->MFMA as in R7 (one qweight dword = one MFMA B-fragment).
// Every wave is fully independent: no __syncthreads anywhere, no spill
// (acc 32 + pA 32 + pB 8 + consts ~10 + addr ~15 ~= 105 VGPR < 128).
// Dequant numerics identical to R6/R7 (exact 2^23 trick, single rounding).
// WS=false fallback: A converted in-loop from fp32 x, atomicAdd epilogue.
template<bool WS>
__global__ __launch_bounds__(256, 4) void gptq_gemm_kernel(
    const float* __restrict__ x, const int* __restrict__ qw,
    const int* __restrict__ qz, const float* __restrict__ scales,
    const unsigned short* __restrict__ xb, float* __restrict__ out)
{
  const int tid  = threadIdx.x;
  const int wave = tid >> 6;
  const int lane = tid & 63;
  const int c    = lane & 15;
  const int quad = lane >> 4;

  const int ks     = blockIdx.x & 7;
  const int ntile  = blockIdx.x >> 3;
  const int n0     = ntile * BN;
  const int kbase0 = ks * KSEG;
  const int grp0   = kbase0 >> 7;          // scale-group base = ks*4

  const int ncol = n0 + wave * 32 + c;     // t=0 col; t=1 is ncol+16

  // A: fragment base for row-tile r is xb[(r*16+c)*KK + kbase0 + i*32 + quad*8]
  const unsigned short* xbb = xb + (size_t)c * KK + kbase0 + quad * 8;
  // B: row (kbase0/8 + quad), col ncol; chunk i advances 4 qw-rows
  const int* qwb = qw + ((size_t)(kbase0 >> 3) + quad) * NN + ncol;

  f32x4 acc[8];   // acc[r*2+t]
  #pragma unroll
  for (int t = 0; t < 8; ++t) acc[t] = {0.f, 0.f, 0.f, 0.f};

  s16x8 pA[2][4];        // A fragments, depth-1 prefetch (WS path)
  int   pB0[4], pB1[4];  // qweight ring, depth-3 (cold HBM stream)
  float pS0[2], pS1[2];  // scales, next-group prefetch (L2-warm)
  int   pZ0[2], pZ1[2];  // qzeros
  float s0, s1, C0, C1;  // current-group dequant constants

  auto ldA = [&](int i) {
    const unsigned short* xp = xbb + i * BK;
    #pragma unroll
    for (int r = 0; r < 4; ++r)
      pA[i & 1][r] = *(const s16x8*)(xp + (size_t)r * 16 * KK);
  };
  auto pfB = [&](int i) {
    const int* qp = qwb + (size_t)i * 4 * NN;
    pB0[i & 3] = qp[0];
    pB1[i & 3] = qp[16];
  };
  auto pfS = [&](int g) {
    const int sl = g & 1;
    const float* sp = scales + (size_t)(grp0 + g) * NN + ncol;
    pS0[sl] = sp[0];
    pS1[sl] = sp[16];
    const int* zp = qz + (size_t)(grp0 + g) * NZROW + (ncol >> 3);
    pZ0[sl] = zp[0];
    pZ1[sl] = zp[2];   // (ncol+16)>>3 == (ncol>>3)+2
  };
  auto setSC = [&](int g) {
    const int sl = g & 1;
    const int sh = (ncol & 7) * 4;       // same nibble for ncol and ncol+16
    s0 = pS0[sl];
    s1 = pS1[sl];
    C0 = __int_as_float(0x4B000000 + ((pZ0[sl] >> sh) & 15) + 1);
    C1 = __int_as_float(0x4B000000 + ((pZ1[sl] >> sh) & 15) + 1);
  };
  auto dq8 = [&](int v, float s, float C) -> i32x4 {
    i32x4 p;
    p.x = pack_bf16(s * (__int_as_float(((v      ) & 15) | 0x4B000000) - C),
                    s * (__int_as_float(((v >>  4) & 15) | 0x4B000000) - C));
    p.y = pack_bf16(s * (__int_as_float(((v >>  8) & 15) | 0x4B000000) - C),
                    s * (__int_as_float(((v >> 12) & 15) | 0x4B000000) - C));
    p.z = pack_bf16(s * (__int_as_float(((v >> 16) & 15) | 0x4B000000) - C),
                    s * (__int_as_float(((v >> 20) & 15) | 0x4B000000) - C));
    p.w = pack_bf16(s * (__int_as_float(((v >> 24) & 15) | 0x4B000000) - C),
                    s * (__int_as_float(((v >> 28) & 15) | 0x4B000000) - C));
    return p;
  };
  // fallback A: convert in-loop from fp32 x
  auto ldA_f32 = [&](int i, int r) -> s16x8 {
    const float* xa = x + (size_t)(r * 16 + c) * KK + kbase0 + i * BK + quad * 8;
    const f32x4 a0 = *(const f32x4*)xa;
    const f32x4 a1 = *(const f32x4*)(xa + 4);
    union { i32x4 i4; s16x8 s8; } ua;
    ua.i4.x = pack_bf16(a0.x, a0.y);
    ua.i4.y = pack_bf16(a0.z, a0.w);
    ua.i4.z = pack_bf16(a1.x, a1.y);
    ua.i4.w = pack_bf16(a1.z, a1.w);
    return ua.s8;
  };

  // ---- prologue ----
  pfS(0);
  pfB(0); pfB(1); pfB(2);
  if (WS) ldA(0);
  setSC(0);
  pfS(1);

  #pragma unroll
  for (int i = 0; i < NCH; ++i) {
    if (i + 3 < NCH) pfB(i + 3);               // deep qw prefetch
    if (WS && i + 1 < NCH) ldA(i + 1);         // A depth-1 (L2-hit latency)

    // B: dequant straight into MFMA B fragments
    union { i32x4 i4; s16x8 s8; } u0, u1;
    u0.i4 = dq8(pB0[i & 3], s0, C0);
    u1.i4 = dq8(pB1[i & 3], s1, C1);

    #pragma unroll
    for (int r = 0; r < 4; ++r) {
      const s16x8 af = WS ? pA[i & 1][r] : ldA_f32(i, r);
      acc[r * 2 + 0] = __builtin_amdgcn_mfma_f32_16x16x32_bf16(af, u0.s8, acc[r * 2 + 0], 0, 0, 0);
      acc[r * 2 + 1] = __builtin_amdgcn_mfma_f32_16x16x32_bf16(af, u1.s8, acc[r * 2 + 1], 0, 0, 0);
    }

    if ((i & 3) == 3) {
      const int g = i >> 2;
      if (g + 1 < NG) { setSC(g + 1); if (g + 2 < NG) pfS(g + 2); }
    }
  }

  // ---- epilogue: rows r*16 + quad*4 + j, cols ncol + t*16 ----
  if (WS) {
    float* wsp = out + (size_t)ks * (MM * NN);
    #pragma unroll
    for (int r = 0; r < 4; ++r) {
      #pragma unroll
      for (int t = 0; t < 2; ++t) {
        const f32x4 a = acc[r * 2 + t];
        float* op = wsp + (size_t)(r * 16 + quad * 4) * NN + ncol + t * 16;
        op[0]      = a.x;
        op[NN]     = a.y;
        op[2 * NN] = a.z;
        op[3 * NN] = a.w;
      }
    }
  } else {
    #pragma unroll
    for (int r = 0; r < 4; ++r) {
      #pragma unroll
      for (int t = 0; t < 2; ++t) {
        const f32x4 a = acc[r * 2 + t];
        float* op = out + (size_t)(r * 16 + quad * 4) * NN + ncol + t * 16;
        atomicAdd(&op[0],          a.x);
        atomicAdd(&op[NN],         a.y);
        atomicAdd(&op[2 * NN],     a.z);
        atomicAdd(&op[3 * NN],     a.w);
      }
    }
  }
}

} // namespace

extern "C" void kernel_launch(void* const* d_in, const int* in_sizes, int n_in,
                              void* d_out, int out_size, void* d_ws, size_t ws_size,
                              hipStream_t stream) {
  const float* x      = (const float*)d_in[0];
  const int*   qw     = (const int*)d_in[1];
  const int*   qz     = (const int*)d_in[2];
  const float* scales = (const float*)d_in[3];
  const float* bias   = (const float*)d_in[4];
  float* out = (float*)d_out;

  if (ws_size >= WS_NEED) {
    float* ws = (float*)d_ws;
    unsigned short* xb = (unsigned short*)((char*)d_ws + XB_OFF_BYTES);
    xcvt_kernel<<<(MM * KK) / 2048, 256, 0, stream>>>(x, xb);
    gptq_gemm_kernel<true><<<NTILES * KSPLIT, 256, 0, stream>>>(x, qw, qz, scales, xb, ws);
    reduce_kernel<<<(MM * NN) / 1024, 256, 0, stream>>>(ws, bias, out);
  } else {
    prep_kernel<<<(MM * NN) / 256, 256, 0, stream>>>(bias, out);
    gptq_gemm_kernel<false><<<NTILES * KSPLIT, 256, 0, stream>>>(x, qw, qz, scales, nullptr, out);
  }
}